// Round 1
// baseline (480.715 us; speedup 1.0000x reference)
//
#include <hip/hip_runtime.h>
#include <stdint.h>

// ---------------------------------------------------------------------------
// WeedLayer: pooled-patch transformer layer + segment-stat scatter. fp32 I/O.
// Sizes: B=8, C=64, H=W=256, PD=32, STRIDE=16 -> n=15, L=225, P=16, E=512,
// HEADS=8, hd=64, fv=4096. Rows matrix X = [patches(128); blocks(1800)].
// ---------------------------------------------------------------------------

typedef __attribute__((ext_vector_type(8))) short bf16x8;
typedef __attribute__((ext_vector_type(4))) float f32x4;

__device__ __forceinline__ unsigned short f2bf(float x) {
    union { float f; unsigned u; } v; v.f = x;
    unsigned r = v.u + 0x7FFFu + ((v.u >> 16) & 1u);   // RNE
    return (unsigned short)(r >> 16);
}

// --- K1: global 4ch x 2x2 pool of features -> Gp bf16 (8,16,128,128) --------
__global__ __launch_bounds__(256) void k_pool_features(
    const float* __restrict__ f, unsigned short* __restrict__ gp)
{
    unsigned t = blockIdx.x * 256u + threadIdx.x;        // 2,097,152 total
    unsigned q = t & 127u, r = (t >> 7) & 127u, g = (t >> 14) & 15u, b = t >> 18;
    const float2* f2 = (const float2*)f;
    float s = 0.f;
    unsigned cb = b * 64u + g * 4u;
#pragma unroll
    for (int j = 0; j < 4; ++j) {
#pragma unroll
        for (int a = 0; a < 2; ++a) {
            unsigned idx = ((cb + j) * 256u + 2u * r + a) * 256u + 2u * q;
            float2 v = f2[idx >> 1];
            s += v.x + v.y;
        }
    }
    gp[t] = f2bf(s * 0.0625f);
}

// --- K2: pool patches -> X rows 0..127 (bf16, 4096 cols) --------------------
__global__ __launch_bounds__(256) void k_pool_patches(
    const float* __restrict__ p, unsigned short* __restrict__ Xb)
{
    unsigned t = blockIdx.x * 256u + threadIdx.x;        // 524,288 total
    unsigned i = t & 4095u, row = t >> 12;               // i = g*256+r*16+q
    unsigned q = i & 15u, r = (i >> 4) & 15u, g = i >> 8;
    const float2* p2 = (const float2*)p;
    float s = 0.f;
    unsigned cb = row * 64u + g * 4u;
#pragma unroll
    for (int j = 0; j < 4; ++j) {
#pragma unroll
        for (int a = 0; a < 2; ++a) {
            unsigned idx = ((cb + j) * 32u + 2u * r + a) * 32u + 2u * q;
            float2 v = p2[idx >> 1];
            s += v.x + v.y;
        }
    }
    Xb[(size_t)row * 4096 + i] = f2bf(s * 0.0625f);
}

// --- K3: gather block crops from Gp -> X rows 128..1927 ---------------------
__global__ __launch_bounds__(256) void k_gather_blocks(
    const unsigned short* __restrict__ Gp, unsigned short* __restrict__ Xb)
{
    unsigned t = blockIdx.x * 256u + threadIdx.x;        // 921,600 groups of 8
    unsigned grp = t & 511u, row_rel = t >> 9;           // row_rel in [0,1800)
    unsigned k0 = grp * 8u;
    unsigned g = k0 >> 8, r = (k0 >> 4) & 15u, q0 = k0 & 15u;
    unsigned b = row_rel / 225u;
    unsigned ij = row_rel - b * 225u;
    unsigned i = ij / 15u, j = ij - i * 15u;
    size_t src = ((size_t)(b * 16u + g) * 128u + i * 8u + r) * 128u + j * 8u + q0;
    size_t dst = (size_t)(128u + row_rel) * 4096u + k0;
    *(uint4*)(Xb + dst) = *(const uint4*)(Gp + src);
}

// --- K4: fp32 -> bf16 weight conversion -------------------------------------
__global__ __launch_bounds__(256) void k_f2bf(
    const float* __restrict__ in, unsigned short* __restrict__ out, int n4)
{
    int t = blockIdx.x * 256 + threadIdx.x;
    if (t >= n4) return;
    float4 v = ((const float4*)in)[t];
    ushort4 o;
    o.x = f2bf(v.x); o.y = f2bf(v.y); o.z = f2bf(v.z); o.w = f2bf(v.w);
    ((ushort4*)out)[t] = o;
}

// --- K5: bf16 NT GEMM: C[M,N] = A[M,K] * B[N,K]^T + bias[N] (fp32 out) ------
// 64x64 tile, BK=32, 4 waves each computing a 32x32 quadrant (2x2 mfma tiles).
__global__ __launch_bounds__(256) void k_gemm_nt(
    const unsigned short* __restrict__ A, const unsigned short* __restrict__ Bw,
    const float* __restrict__ bias, float* __restrict__ C,
    int M, int N, int K)
{
    __shared__ __align__(16) unsigned short As[64 * 32];
    __shared__ __align__(16) unsigned short Bs[64 * 32];
    const int tid  = threadIdx.x;
    const int bm   = blockIdx.y, bn = blockIdx.x;
    const int wave = tid >> 6, lane = tid & 63;
    const int wm   = (wave >> 1) * 32, wn = (wave & 1) * 32;
    const int l15  = lane & 15, kq = (lane >> 4) * 8;

    const int srow = tid >> 2;            // 0..63
    const int scol = (tid & 3) * 8;       // 0,8,16,24
    const int arow = bm * 64 + srow;
    const bool aval = arow < M;
    const unsigned short* Ap = A + (size_t)(aval ? arow : 0) * K + scol;
    const unsigned short* Bp = Bw + (size_t)(bn * 64 + srow) * K + scol;

    f32x4 acc[2][2];
#pragma unroll
    for (int i = 0; i < 2; ++i)
#pragma unroll
        for (int j = 0; j < 2; ++j) acc[i][j] = (f32x4){0.f, 0.f, 0.f, 0.f};

    for (int k0 = 0; k0 < K; k0 += 32) {
        if (aval) {
            *(uint4*)&As[srow * 32 + scol] = *(const uint4*)(Ap + k0);
        } else {
            uint4 z; z.x = 0; z.y = 0; z.z = 0; z.w = 0;
            *(uint4*)&As[srow * 32 + scol] = z;
        }
        *(uint4*)&Bs[srow * 32 + scol] = *(const uint4*)(Bp + k0);
        __syncthreads();
        bf16x8 a0 = *(const bf16x8*)&As[(wm + l15) * 32 + kq];
        bf16x8 a1 = *(const bf16x8*)&As[(wm + 16 + l15) * 32 + kq];
        bf16x8 b0 = *(const bf16x8*)&Bs[(wn + l15) * 32 + kq];
        bf16x8 b1 = *(const bf16x8*)&Bs[(wn + 16 + l15) * 32 + kq];
        acc[0][0] = __builtin_amdgcn_mfma_f32_16x16x32_bf16(a0, b0, acc[0][0], 0, 0, 0);
        acc[0][1] = __builtin_amdgcn_mfma_f32_16x16x32_bf16(a0, b1, acc[0][1], 0, 0, 0);
        acc[1][0] = __builtin_amdgcn_mfma_f32_16x16x32_bf16(a1, b0, acc[1][0], 0, 0, 0);
        acc[1][1] = __builtin_amdgcn_mfma_f32_16x16x32_bf16(a1, b1, acc[1][1], 0, 0, 0);
        __syncthreads();
    }
    // epilogue: C/D layout col=lane&15, row=(lane>>4)*4+reg
#pragma unroll
    for (int it = 0; it < 2; ++it) {
        int rowb = bm * 64 + wm + it * 16 + (lane >> 4) * 4;
#pragma unroll
        for (int iu = 0; iu < 2; ++iu) {
            int col = bn * 64 + wn + iu * 16 + l15;
            float bv = bias[col];
#pragma unroll
            for (int r = 0; r < 4; ++r) {
                int row = rowb + r;
                if (row < M) C[(size_t)row * N + col] = acc[it][iu][r] + bv;
            }
        }
    }
}

// --- K6: LayerNorm over 512 cols (wave per row), optional residual add ------
__global__ __launch_bounds__(256) void k_ln(
    const float* __restrict__ X, const float* __restrict__ R,
    const float* __restrict__ gg, const float* __restrict__ bb,
    float* __restrict__ outF, unsigned short* __restrict__ outB, int rows)
{
    int wave = threadIdx.x >> 6, lane = threadIdx.x & 63;
    int row = blockIdx.x * 4 + wave;
    if (row >= rows) return;
    const float* xp = X + (size_t)row * 512 + lane * 8;
    float v[8];
    { float4 a = *(const float4*)xp, b = *(const float4*)(xp + 4);
      v[0]=a.x; v[1]=a.y; v[2]=a.z; v[3]=a.w; v[4]=b.x; v[5]=b.y; v[6]=b.z; v[7]=b.w; }
    if (R) {
        const float* rp = R + (size_t)row * 512 + lane * 8;
        float4 a = *(const float4*)rp, b = *(const float4*)(rp + 4);
        v[0]+=a.x; v[1]+=a.y; v[2]+=a.z; v[3]+=a.w; v[4]+=b.x; v[5]+=b.y; v[6]+=b.z; v[7]+=b.w;
    }
    float s = 0.f;
#pragma unroll
    for (int i = 0; i < 8; ++i) s += v[i];
#pragma unroll
    for (int m = 32; m; m >>= 1) s += __shfl_xor(s, m, 64);
    float mu = s * (1.f / 512.f);
    float sq = 0.f;
#pragma unroll
    for (int i = 0; i < 8; ++i) { float d = v[i] - mu; sq += d * d; }
#pragma unroll
    for (int m = 32; m; m >>= 1) sq += __shfl_xor(sq, m, 64);
    float rstd = rsqrtf(sq * (1.f / 512.f) + 1e-5f);
    const float* gp = gg + lane * 8;
    const float* bp = bb + lane * 8;
    float4 g0 = *(const float4*)gp, g1 = *(const float4*)(gp + 4);
    float4 b0 = *(const float4*)bp, b1 = *(const float4*)(bp + 4);
    float ga[8] = {g0.x,g0.y,g0.z,g0.w,g1.x,g1.y,g1.z,g1.w};
    float ba[8] = {b0.x,b0.y,b0.z,b0.w,b1.x,b1.y,b1.z,b1.w};
    float o[8];
#pragma unroll
    for (int i = 0; i < 8; ++i) o[i] = (v[i] - mu) * rstd * ga[i] + ba[i];
    float* ofp = outF + (size_t)row * 512 + lane * 8;
    float4 w0; w0.x=o[0]; w0.y=o[1]; w0.z=o[2]; w0.w=o[3];
    float4 w1; w1.x=o[4]; w1.y=o[5]; w1.z=o[6]; w1.w=o[7];
    *(float4*)ofp = w0; *(float4*)(ofp + 4) = w1;
    unsigned short* obp = outB + (size_t)row * 512 + lane * 8;
    ushort4 u0, u1;
    u0.x=f2bf(o[0]); u0.y=f2bf(o[1]); u0.z=f2bf(o[2]); u0.w=f2bf(o[3]);
    u1.x=f2bf(o[4]); u1.y=f2bf(o[5]); u1.z=f2bf(o[6]); u1.w=f2bf(o[7]);
    ((ushort4*)obp)[0] = u0; ((ushort4*)obp)[1] = u1;
}

// --- K7: attention per (b,h): scores(16x225) -> softmax -> @V, bf16 out -----
__global__ __launch_bounds__(256) void k_attn(
    const float* __restrict__ q, const float* __restrict__ kv,
    unsigned short* __restrict__ attn_bf)
{
    int b = blockIdx.x, h = blockIdx.y;
    __shared__ __align__(16) float qs[16 * 64];
    __shared__ float sc[16 * 225];
    int t = threadIdx.x;
    for (int i = t; i < 1024; i += 256) {
        int p = i >> 6, d = i & 63;
        qs[i] = q[(size_t)(b * 16 + p) * 512 + h * 64 + d];
    }
    __syncthreads();
    for (int i = t; i < 3600; i += 256) {
        int p = i / 225, l = i - p * 225;
        const float4* k4 = (const float4*)(kv + (size_t)(b * 225 + l) * 1024 + h * 64);
        const float4* q4 = (const float4*)&qs[p * 64];
        float s = 0.f;
#pragma unroll
        for (int d = 0; d < 16; ++d) {
            float4 kk = k4[d], qq = q4[d];
            s += kk.x * qq.x + kk.y * qq.y + kk.z * qq.z + kk.w * qq.w;
        }
        sc[p * 225 + l] = s * 0.125f;   // 1/sqrt(64)
    }
    __syncthreads();
    // softmax: 16 lanes per row
    int lane = t & 63, wave = t >> 6;
    int p = wave * 4 + (lane >> 4), sub = lane & 15;
    float m = -1e30f;
    for (int l = sub; l < 225; l += 16) m = fmaxf(m, sc[p * 225 + l]);
#pragma unroll
    for (int off = 8; off; off >>= 1) m = fmaxf(m, __shfl_xor(m, off, 16));
    float s = 0.f;
    for (int l = sub; l < 225; l += 16) {
        float e = __expf(sc[p * 225 + l] - m);
        sc[p * 225 + l] = e; s += e;
    }
#pragma unroll
    for (int off = 8; off; off >>= 1) s += __shfl_xor(s, off, 16);
    float inv = 1.f / s;
    for (int l = sub; l < 225; l += 16) sc[p * 225 + l] *= inv;
    __syncthreads();
    for (int i = t; i < 1024; i += 256) {
        int p2 = i >> 6, d = i & 63;
        const float* vp = kv + (size_t)(b * 225) * 1024 + 512 + h * 64 + d;
        float o = 0.f;
        for (int l = 0; l < 225; ++l) o += sc[p2 * 225 + l] * vp[(size_t)l * 1024];
        attn_bf[(size_t)(b * 16 + p2) * 512 + h * 64 + d] = f2bf(o);
    }
}

// --- K8: x = gelu(M1) + res --------------------------------------------------
__global__ __launch_bounds__(256) void k_gelu_res(
    const float* __restrict__ m1, const float* __restrict__ res, float* __restrict__ x)
{
    int t = blockIdx.x * 256 + threadIdx.x;
    float v = m1[t];
    float g = 0.5f * v * (1.f + erff(v * 0.70710678118654752f));
    x[t] = g + res[t];
}

// --- K9: outs[128,2] = x @ Wc^T + bc ----------------------------------------
__global__ __launch_bounds__(256) void k_wc(
    const float* __restrict__ x, const float* __restrict__ Wc,
    const float* __restrict__ bc, float* __restrict__ outs)
{
    int t = threadIdx.x;                  // 256 = 128 rows x 2 cols
    int row = t >> 1, c = t & 1;
    const float* xp = x + (size_t)row * 512;
    const float* wp = Wc + (size_t)c * 512;
    float s = 0.f;
    for (int k = 0; k < 512; ++k) s += xp[k] * wp[k];
    outs[row * 2 + c] = s + bc[c];
}

// --- K10: zero helper --------------------------------------------------------
__global__ void k_zero(float* __restrict__ p, int n) {
    int t = blockIdx.x * blockDim.x + threadIdx.x;
    if (t < n) p[t] = 0.f;
}

// --- K11: segment histogram (sums of probs + counts per (b,label)) ----------
__global__ __launch_bounds__(256) void k_hist(
    const int* __restrict__ masks, const float* __restrict__ probs,
    float* __restrict__ sums, float* __restrict__ cnt)
{
    __shared__ float ls[68];              // 17*3 sums + 17 cnt
    int t = threadIdx.x;
    if (t < 68) ls[t] = 0.f;
    __syncthreads();
    int b = blockIdx.x >> 6, chunk = blockIdx.x & 63;
    int base = chunk * 1024;
    for (int it = 0; it < 4; ++it) {
        int px = base + it * 256 + t;
        int lab = masks[b * 65536 + px];
        atomicAdd(&ls[lab * 3 + 0], probs[(size_t)(b * 3 + 0) * 65536 + px]);
        atomicAdd(&ls[lab * 3 + 1], probs[(size_t)(b * 3 + 1) * 65536 + px]);
        atomicAdd(&ls[lab * 3 + 2], probs[(size_t)(b * 3 + 2) * 65536 + px]);
        atomicAdd(&ls[51 + lab], 1.f);
    }
    __syncthreads();
    if (t < 51)       atomicAdd(&sums[b * 51 + t], ls[t]);
    else if (t < 68)  atomicAdd(&cnt[b * 17 + t - 51], ls[t]);
}

// --- K12: build newv_full table (8 x 17 x 3) --------------------------------
__global__ void k_newv(
    const float* __restrict__ seg, const float* __restrict__ outs,
    float* __restrict__ newv)
{
    int t = threadIdx.x;
    if (t >= 136) return;                 // t = b*17 + lab
    int lab = t % 17;
    const float* sums = seg;
    const float* cnt  = seg + 408;
    if (lab == 0) { newv[t*3+0] = 0.f; newv[t*3+1] = 0.f; newv[t*3+2] = 0.f; return; }
    int b = t / 17;
    float c  = fmaxf(cnt[t], 1.f);
    float m0 = sums[t*3+0] / c + 1e-6f;
    float m1 = sums[t*3+1] / c + 1e-6f;
    float m2 = sums[t*3+2] / c + 1e-6f;
    int p = lab - 1;
    float o0 = outs[(b*16+p)*2+0], o1 = outs[(b*16+p)*2+1];
    float new0 = m0 / (0.5f * (m1 + m2)) * (0.5f * (o0 + o1));
    newv[t*3+0] = new0; newv[t*3+1] = o0; newv[t*3+2] = o1;
}

// --- K13: final per-pixel gather --------------------------------------------
__global__ __launch_bounds__(256) void k_out(
    const int* __restrict__ masks, const float* __restrict__ probs,
    const float* __restrict__ newv, float* __restrict__ out)
{
    int t = blockIdx.x * 256 + threadIdx.x;   // 524,288 pixels
    int b = t >> 16, hw = t & 65535;
    int lab = masks[t];
    if (lab > 0) {
        const float* nv = newv + (size_t)(b * 17 + lab) * 3;
        out[(size_t)(b*3+0)*65536 + hw] = nv[0];
        out[(size_t)(b*3+1)*65536 + hw] = nv[1];
        out[(size_t)(b*3+2)*65536 + hw] = nv[2];
    } else {
        out[(size_t)(b*3+0)*65536 + hw] = probs[(size_t)(b*3+0)*65536 + hw];
        out[(size_t)(b*3+1)*65536 + hw] = probs[(size_t)(b*3+1)*65536 + hw];
        out[(size_t)(b*3+2)*65536 + hw] = probs[(size_t)(b*3+2)*65536 + hw];
    }
}

// ---------------------------------------------------------------------------
extern "C" void kernel_launch(void* const* d_in, const int* in_sizes, int n_in,
                              void* d_out, int out_size, void* d_ws, size_t ws_size,
                              hipStream_t stream)
{
    const float* features = (const float*)d_in[0];
    const float* probs    = (const float*)d_in[1];
    const float* patches  = (const float*)d_in[2];
    const int*   masks    = (const int*)d_in[3];
    const float* ln_g     = (const float*)d_in[4];
    const float* ln_b     = (const float*)d_in[5];
    const float* Wr       = (const float*)d_in[6];
    const float* br       = (const float*)d_in[7];
    const float* Wqkv     = (const float*)d_in[8];
    const float* bqkv     = (const float*)d_in[9];
    const float* Wo       = (const float*)d_in[10];
    const float* bo       = (const float*)d_in[11];
    const float* Wm       = (const float*)d_in[12];
    const float* bm       = (const float*)d_in[13];
    const float* Wc       = (const float*)d_in[14];
    const float* bc       = (const float*)d_in[15];
    float* out = (float*)d_out;

    char* w = (char*)d_ws;
    size_t off = 0;
    auto alloc = [&](size_t bytes) -> char* {
        char* p = w + off;
        off += (bytes + 255) & ~(size_t)255;
        return p;
    };
    unsigned short* Gp     = (unsigned short*)alloc((size_t)2097152 * 2);
    unsigned short* Xb     = (unsigned short*)alloc((size_t)1928 * 4096 * 2);
    unsigned short* Wr_b   = (unsigned short*)alloc((size_t)2097152 * 2);
    unsigned short* Wqkv_b = (unsigned short*)alloc((size_t)786432 * 2);
    unsigned short* Wo_b   = (unsigned short*)alloc((size_t)262144 * 2);
    unsigned short* Wm_b   = (unsigned short*)alloc((size_t)262144 * 2);
    float* Y    = (float*)alloc((size_t)1928 * 512 * 4);
    float* LNf  = (float*)alloc((size_t)1928 * 512 * 4);
    unsigned short* LNb = (unsigned short*)alloc((size_t)1928 * 512 * 2);
    float* qbuf = (float*)alloc((size_t)65536 * 4);
    float* kv   = (float*)alloc((size_t)1800 * 1024 * 4);
    unsigned short* attnb = (unsigned short*)alloc((size_t)65536 * 2);
    float* Zo   = (float*)alloc((size_t)65536 * 4);
    float* resf = (float*)alloc((size_t)65536 * 4);
    unsigned short* resb = (unsigned short*)alloc((size_t)65536 * 2);
    float* M1   = (float*)alloc((size_t)65536 * 4);
    float* xbuf = (float*)alloc((size_t)65536 * 4);
    float* outsB = (float*)alloc((size_t)256 * 4);
    float* seg   = (float*)alloc((size_t)544 * 4);   // 408 sums + 136 cnt
    float* newv  = (float*)alloc((size_t)408 * 4);

    // zero segment accumulators (ws is poisoned each call)
    k_zero<<<3, 256, 0, stream>>>(seg, 544);

    // pooling + block gather + weight conversion
    k_pool_features<<<8192, 256, 0, stream>>>(features, Gp);
    k_pool_patches<<<2048, 256, 0, stream>>>(patches, Xb);
    k_gather_blocks<<<3600, 256, 0, stream>>>(Gp, Xb);
    k_f2bf<<<2048, 256, 0, stream>>>(Wr, Wr_b, 524288);
    k_f2bf<<<768, 256, 0, stream>>>(Wqkv, Wqkv_b, 196608);
    k_f2bf<<<256, 256, 0, stream>>>(Wo, Wo_b, 65536);
    k_f2bf<<<256, 256, 0, stream>>>(Wm, Wm_b, 65536);

    // GEMM1: Y = X @ Wr^T + br   (1928 x 4096 x 512)
    k_gemm_nt<<<dim3(8, 31), 256, 0, stream>>>(Xb, Wr_b, br, Y, 1928, 512, 4096);
    // LN1 -> pe (rows 0..127) / be (rows 128..1927), fp32 + bf16
    k_ln<<<482, 256, 0, stream>>>(Y, nullptr, ln_g, ln_b, LNf, LNb, 1928);

    // K,V = be @ [Wk;Wv]^T  (1800 x 512 x 1024)
    k_gemm_nt<<<dim3(16, 29), 256, 0, stream>>>(LNb + (size_t)128 * 512, Wqkv_b + (size_t)512 * 512,
                                                bqkv + 512, kv, 1800, 1024, 512);
    // Q = pe @ Wq^T  (128 x 512 x 512)
    k_gemm_nt<<<dim3(8, 2), 256, 0, stream>>>(LNb, Wqkv_b, bqkv, qbuf, 128, 512, 512);

    // attention
    k_attn<<<dim3(8, 8), 256, 0, stream>>>(qbuf, kv, attnb);

    // Wo projection + residual LN
    k_gemm_nt<<<dim3(8, 2), 256, 0, stream>>>(attnb, Wo_b, bo, Zo, 128, 512, 512);
    k_ln<<<32, 256, 0, stream>>>(Zo, LNf, ln_g, ln_b, resf, resb, 128);

    // MLP: gelu(res @ Wm^T + bm) + res
    k_gemm_nt<<<dim3(8, 2), 256, 0, stream>>>(resb, Wm_b, bm, M1, 128, 512, 512);
    k_gelu_res<<<256, 256, 0, stream>>>(M1, resf, xbuf);
    k_wc<<<1, 256, 0, stream>>>(xbuf, Wc, bc, outsB);

    // segment stats + final gather
    k_hist<<<512, 256, 0, stream>>>(masks, probs, seg, seg + 408);
    k_newv<<<1, 256, 0, stream>>>(seg, outsB, newv);
    k_out<<<2048, 256, 0, stream>>>(masks, probs, newv, out);
}